// Round 6
// baseline (13492.346 us; speedup 1.0000x reference)
//
#include <hip/hip_runtime.h>
#include <hip/hip_fp16.h>

#define B_ 256
#define T_ 512
#define D_ 128
#define H_ 2048
#define C_ 128
#define BSTRIDE 2052   // byte stride 4104 ≡ 8 (mod 128): skewed bank mapping for b128 reads

typedef _Float16 half8 __attribute__((ext_vector_type(8)));
typedef float floatx4 __attribute__((ext_vector_type(4)));

// IF$-coherent (agent-scope) h loads: bypass L1/L2, always read the device coherence point.
__device__ __forceinline__ half8 llc_load16(const _Float16* p) {
    union { unsigned long long u[2]; half8 h; } v;
    const unsigned long long* q = (const unsigned long long*)p;
    v.u[0] = __hip_atomic_load(q,     __ATOMIC_RELAXED, __HIP_MEMORY_SCOPE_AGENT);
    v.u[1] = __hip_atomic_load(q + 1, __ATOMIC_RELAXED, __HIP_MEMORY_SCOPE_AGENT);
    return v.h;
}

// ---- h0 = tanh(W_hx[x[:,0]] + b_h) fp16; zero the 512 barrier counter slots ----
__global__ void init_h(const int* __restrict__ x, const float* __restrict__ W_hx,
                       const float* __restrict__ b_h, _Float16* __restrict__ h0,
                       unsigned* __restrict__ cnt) {
    int idx = blockIdx.x * blockDim.x + threadIdx.x;   // over B_*H_
    if (idx < 512) cnt[idx] = 0;
    int b = idx >> 11, j = idx & (H_ - 1);
    int xv = x[b * T_];                                // t = 0
    h0[idx] = (_Float16)tanhf(W_hx[(size_t)xv * H_ + j] + b_h[j]);
}

#define LOAD_BLK(dst, blk)                                                  \
    _Pragma("unroll") for (int u = 0; u < 8; ++u)                           \
        dst[u] = llc_load16(ap + ((blk) * 8 + u) * 32);

#define COMP_BLK(src, blk)                                                  \
    _Pragma("unroll") for (int u = 0; u < 8; ++u) {                         \
        half8 b0v = *(const half8*)(bp0 + ((blk) * 8 + u) * 32);            \
        half8 b1v = *(const half8*)(bp1 + ((blk) * 8 + u) * 32);            \
        acc0 = __builtin_amdgcn_mfma_f32_16x16x32_f16(src[u], b0v, acc0, 0, 0, 0); \
        acc1 = __builtin_amdgcn_mfma_f32_16x16x32_f16(src[u], b1v, acc1, 0, 0, 0); \
    }

// ---- recurrence: 256 WGs (1/CU) x 256 thr; WG tile 64(M) x 32(N); W_hh^T slice in LDS ----
// h stores: NORMAL (dirty L2); publish via per-WG fence(release,agent) = waitcnt + buffer_wbl2 sc1
// (the r4-proven path). h loads: sc0sc1 agent atomics (IF$-fresh) => NO acquire-inv anywhere,
// so read-only W_hx/x stay warm in L1/L2 for all 511 steps. Per-rowblock barrier (64 arrivals).
__global__ __launch_bounds__(256, 1)
void rnn_steps(const float* __restrict__ W_hh, _Float16* __restrict__ h0,
               _Float16* __restrict__ h1, const int* __restrict__ x,
               const float* __restrict__ W_hx, const float* __restrict__ b_h,
               unsigned* __restrict__ cnt) {
    extern __shared__ _Float16 bs[];   // [32 cols][BSTRIDE k]
    const int bid = blockIdx.x;
    const int grp = bid & 7;
    const int g   = bid >> 3;
    const int colblock = grp * 8 + (g & 7);  // 0..63
    const int rowblock = g >> 3;             // 0..3  (== bid>>6)
    const int nb  = colblock * 32;
    const int tid = threadIdx.x;

    // one-time: load + convert + transpose W_hh slice (32 cols, all K) into LDS
    {
        const int c  = (tid & 7) * 4;
        const int kr = tid >> 3;             // 0..31
        for (int k = kr; k < H_; k += 32) {
            const float4 wv = *(const float4*)(W_hh + (size_t)k * H_ + nb + c);
            bs[(c + 0) * BSTRIDE + k] = (_Float16)wv.x;
            bs[(c + 1) * BSTRIDE + k] = (_Float16)wv.y;
            bs[(c + 2) * BSTRIDE + k] = (_Float16)wv.z;
            bs[(c + 3) * BSTRIDE + k] = (_Float16)wv.w;
        }
    }
    __syncthreads();

    const int w    = tid >> 6;               // wave 0..3 -> rows w*16..w*16+15
    const int l    = tid & 63;
    const int l15  = l & 15;
    const int kl   = (l >> 4) << 3;          // lane k-offset within K=32 step
    const int rbase = rowblock * 64 + w * 16;
    const int arow  = rbase + l15;
    const int r0    = rbase + ((l >> 4) << 2);   // C-frag row base for this lane
    const _Float16* bp0 = bs + l15 * BSTRIDE + kl;          // cols nb+0..15
    const _Float16* bp1 = bs + (16 + l15) * BSTRIDE + kl;   // cols nb+16..31
    const int c0 = nb + l15;
    const float bh0 = b_h[c0], bh1 = b_h[c0 + 16];

    unsigned* mycnt = cnt + rowblock * 64;   // one counter per rowblock, 256B apart

    for (int t = 1; t < T_; ++t) {
        const _Float16* __restrict__ hc = (t & 1) ? h0 : h1;  // h after step t-1
        _Float16* __restrict__ hn       = (t & 1) ? h1 : h0;

        // epilogue-gather prefetch (normal cached loads; stay warm — no inv in this kernel)
        int   xv[4];
        float wx0[4], wx1[4];
#pragma unroll
        for (int jj = 0; jj < 4; ++jj) xv[jj] = x[(r0 + jj) * T_ + t];
#pragma unroll
        for (int jj = 0; jj < 4; ++jj) {
            wx0[jj] = W_hx[(size_t)xv[jj] * H_ + c0];
            wx1[jj] = W_hx[(size_t)xv[jj] * H_ + c0 + 16];
        }

        const _Float16* ap = hc + (size_t)arow * H_ + kl;
        floatx4 acc0 = {0.f, 0.f, 0.f, 0.f}, acc1 = {0.f, 0.f, 0.f, 0.f};

        // K-loop: 8 blocks x 8 frags, register ping-pong; next block's 16 IF$ loads
        // issue ahead of current block's MFMAs -> ~700cy latency hidden.
        half8 aA[8], aB[8];
        LOAD_BLK(aA, 0);
#pragma unroll
        for (int sb = 0; sb < 4; ++sb) {
            LOAD_BLK(aB, 2 * sb + 1);
            COMP_BLK(aA, 2 * sb);
            if (sb < 3) { LOAD_BLK(aA, 2 * sb + 2); }
            COMP_BLK(aB, 2 * sb + 1);
        }

#pragma unroll
        for (int jj = 0; jj < 4; ++jj) {
            float z0 = acc0[jj] + wx0[jj] + bh0;
            float z1 = acc1[jj] + wx1[jj] + bh1;
            hn[(size_t)(r0 + jj) * H_ + c0]      = (_Float16)tanhf(z0);   // normal stores
            hn[(size_t)(r0 + jj) * H_ + c0 + 16] = (_Float16)tanhf(z1);
        }

        // ---- barrier: publish-with-wbl2 release (r4-proven), relaxed spin, no inv ----
        __syncthreads();                     // all 4 waves' stores drained into L2
        if (tid == 0) {
            __builtin_amdgcn_fence(__ATOMIC_RELEASE, "agent");   // waitcnt + buffer_wbl2 sc1
            __hip_atomic_fetch_add(mycnt, 1u, __ATOMIC_RELAXED, __HIP_MEMORY_SCOPE_AGENT);
            while (__hip_atomic_load(mycnt, __ATOMIC_RELAXED, __HIP_MEMORY_SCOPE_AGENT)
                   < (unsigned)(64 * t))
                __builtin_amdgcn_s_sleep(2); // relaxed poll: no cache maintenance
            __builtin_amdgcn_fence(__ATOMIC_ACQUIRE, "workgroup"); // order only; h reads are sc1
        }
        __syncthreads();
    }
}

// ---- out[b,c] = h[b,:] @ W_ph + b_p (fp32) ----
__global__ void final_proj(const _Float16* __restrict__ h, const float* __restrict__ W_ph,
                           const float* __restrict__ b_p, float* __restrict__ out) {
    __shared__ float part[C_];
    const int b  = blockIdx.x;
    const int c  = threadIdx.x & (C_ - 1);
    const int hh = threadIdx.x >> 7;
    const int j0 = hh * (H_ / 2);
    float acc = 0.f;
#pragma unroll 4
    for (int j = j0; j < j0 + H_ / 2; ++j)
        acc = fmaf((float)h[(size_t)b * H_ + j], W_ph[j * C_ + c], acc);
    if (hh) part[c] = acc;
    __syncthreads();
    if (!hh) out[b * C_ + c] = acc + part[c] + b_p[c];
}

extern "C" void kernel_launch(void* const* d_in, const int* in_sizes, int n_in,
                              void* d_out, int out_size, void* d_ws, size_t ws_size,
                              hipStream_t stream) {
    const int*   x    = (const int*)d_in[0];
    const float* W_hx = (const float*)d_in[1];
    const float* W_hh = (const float*)d_in[2];
    const float* W_ph = (const float*)d_in[3];
    const float* b_h  = (const float*)d_in[4];
    const float* b_p  = (const float*)d_in[5];
    float* out = (float*)d_out;

    char* ws = (char*)d_ws;
    _Float16* h0  = (_Float16*)ws;                                   // 1 MB
    _Float16* h1  = (_Float16*)(ws + (size_t)B_ * H_ * 2);           // 1 MB
    unsigned* cnt = (unsigned*)(ws + (size_t)2 * B_ * H_ * 2);       // 2 KB (512 u32)

    init_h<<<(B_ * H_) / 256, 256, 0, stream>>>(x, W_hx, b_h, h0, cnt);

    const int smem = 32 * BSTRIDE * 2;   // 131328 B
    hipFuncSetAttribute((const void*)rnn_steps,
                        hipFuncAttributeMaxDynamicSharedMemorySize, smem);

    const float* whh = W_hh; _Float16* ph0 = h0; _Float16* ph1 = h1;
    const int* px = x; const float* pwhx = W_hx; const float* pbh = b_h;
    unsigned* pcnt = cnt;
    void* args[] = {(void*)&whh, (void*)&ph0, (void*)&ph1,
                    (void*)&px, (void*)&pwhx, (void*)&pbh, (void*)&pcnt};
    hipError_t e = hipLaunchCooperativeKernel((void*)rnn_steps, dim3(256), dim3(256),
                                              args, smem, stream);
    if (e != hipSuccess) {
        // fallback: plain launch — 1 WG/CU x 256 WGs co-schedules on 256 CUs
        rnn_steps<<<dim3(256), dim3(256), smem, stream>>>(whh, ph0, ph1, px, pwhx, pbh, pcnt);
    }

    // h after t=511 lives in h1
    final_proj<<<B_, 256, 0, stream>>>(h1, W_ph, b_p, out);
}

// Round 7
// 10391.798 us; speedup vs baseline: 1.2984x; 1.2984x over previous
//
#include <hip/hip_runtime.h>
#include <hip/hip_fp16.h>

#define B_ 256
#define T_ 512
#define D_ 128
#define H_ 2048
#define C_ 128
#define BSTRIDE 2052   // byte stride 4104 ≡ 8 (mod 128): skewed bank mapping, b128 reads conflict-free

typedef _Float16 half8 __attribute__((ext_vector_type(8)));
typedef float floatx4 __attribute__((ext_vector_type(4)));

// h storage layout is K-permuted: within each 32-col block, storage 2j <- col j, 2j+1 <- col j+16.
//   sigma(s)  = (s & ~31) + ((s & 31) >> 1) + ((s & 1) << 4)      (storage -> original col)
//   sigma^-1(k) = (k & ~31) | ((k & 15) << 1) | ((k >> 4) & 1)    (original col -> storage)
// The GEMM is K-order-invariant: LDS W_hh is built in the same storage order.

// IF$-coherent h loads (sc0 sc1): bypass L1/L2, always read the device coherence point.
__device__ __forceinline__ half8 llc_load16(const _Float16* p) {
    union { unsigned long long u[2]; half8 h; } v;
    const unsigned long long* q = (const unsigned long long*)p;
    v.u[0] = __hip_atomic_load(q,     __ATOMIC_RELAXED, __HIP_MEMORY_SCOPE_AGENT);
    v.u[1] = __hip_atomic_load(q + 1, __ATOMIC_RELAXED, __HIP_MEMORY_SCOPE_AGENT);
    return v.h;
}

// ---- h0 = tanh(W_hx[x[:,0]] + b_h) in PERMUTED layout; zero the 512 barrier counter slots ----
__global__ void init_h(const int* __restrict__ x, const float* __restrict__ W_hx,
                       const float* __restrict__ b_h, _Float16* __restrict__ h0,
                       unsigned* __restrict__ cnt) {
    int idx = blockIdx.x * blockDim.x + threadIdx.x;   // over B_*H_ (storage index)
    if (idx < 512) cnt[idx] = 0;
    int b = idx >> 11, s = idx & (H_ - 1);
    int j = (s & ~31) + ((s & 31) >> 1) + ((s & 1) << 4);   // original col
    int xv = x[b * T_];                                     // t = 0
    h0[idx] = (_Float16)tanhf(W_hx[(size_t)xv * H_ + j] + b_h[j]);
}

#define LOAD_BLK(dst, blk)                                                  \
    _Pragma("unroll") for (int u = 0; u < 8; ++u)                           \
        dst[u] = llc_load16(ap + ((blk) * 8 + u) * 32);

#define COMP_BLK(src, blk)                                                  \
    _Pragma("unroll") for (int u = 0; u < 8; ++u) {                         \
        half8 b0v = *(const half8*)(bp0 + ((blk) * 8 + u) * 32);            \
        half8 b1v = *(const half8*)(bp1 + ((blk) * 8 + u) * 32);            \
        acc0 = __builtin_amdgcn_mfma_f32_16x16x32_f16(src[u], b0v, acc0, 0, 0, 0); \
        acc1 = __builtin_amdgcn_mfma_f32_16x16x32_f16(src[u], b1v, acc1, 0, 0, 0); \
    }

// ---- recurrence: 256 WGs (1/CU) x 256 thr; WG tile 64(M) x 32(N); W_hh^T slice in LDS ----
// h publish: packed u32 agent-scope atomic SWAPS (execute AT the IF$; returning form pinned).
// => zero wbl2 / zero inv per step. h reads: sc0sc1 (IF$-fresh). x/W_hx stay warm in L1/L2.
// Per-rowblock monotonic barrier (64 arrivals), relaxed polls, workgroup-only fences.
__global__ __launch_bounds__(256, 1)
void rnn_steps(const float* __restrict__ W_hh, _Float16* __restrict__ h0,
               _Float16* __restrict__ h1, const int* __restrict__ x,
               const float* __restrict__ W_hx, const float* __restrict__ b_h,
               unsigned* __restrict__ cnt) {
    extern __shared__ _Float16 bs[];   // [32 cols][BSTRIDE storage-k]
    const int bid = blockIdx.x;
    const int grp = bid & 7;
    const int g   = bid >> 3;
    const int colblock = grp * 8 + (g & 7);  // 0..63
    const int rowblock = g >> 3;             // 0..3  (== bid>>6)
    const int nb  = colblock * 32;
    const int tid = threadIdx.x;

    // one-time: load + convert + transpose W_hh slice into LDS, K in STORAGE order
    {
        const int c  = (tid & 7) * 4;
        const int kr = tid >> 3;             // 0..31
        for (int k = kr; k < H_; k += 32) {
            int s = (k & ~31) | ((k & 15) << 1) | ((k >> 4) & 1);   // sigma^-1(k)
            const float4 wv = *(const float4*)(W_hh + (size_t)k * H_ + nb + c);
            bs[(c + 0) * BSTRIDE + s] = (_Float16)wv.x;
            bs[(c + 1) * BSTRIDE + s] = (_Float16)wv.y;
            bs[(c + 2) * BSTRIDE + s] = (_Float16)wv.z;
            bs[(c + 3) * BSTRIDE + s] = (_Float16)wv.w;
        }
    }
    __syncthreads();

    const int w    = tid >> 6;               // wave 0..3 -> rows w*16..w*16+15
    const int l    = tid & 63;
    const int l15  = l & 15;
    const int kl   = (l >> 4) << 3;          // lane storage-k offset within K=32 step
    const int rbase = rowblock * 64 + w * 16;
    const int arow  = rbase + l15;
    const int r0    = rbase + ((l >> 4) << 2);   // C-frag row base for this lane
    const _Float16* bp0 = bs + l15 * BSTRIDE + kl;          // cols nb+0..15
    const _Float16* bp1 = bs + (16 + l15) * BSTRIDE + kl;   // cols nb+16..31
    const int c0 = nb + l15;
    const float bh0 = b_h[c0], bh1 = b_h[c0 + 16];

    unsigned* mycnt = cnt + rowblock * 64;   // one counter per rowblock, 256B apart

    for (int t = 1; t < T_; ++t) {
        const _Float16* __restrict__ hc = (t & 1) ? h0 : h1;  // h after step t-1
        _Float16* __restrict__ hn       = (t & 1) ? h1 : h0;

        // epilogue-gather prefetch (warm cached loads; nothing invalidates them anymore)
        int   xv[4];
        float wx0[4], wx1[4];
#pragma unroll
        for (int jj = 0; jj < 4; ++jj) xv[jj] = x[(r0 + jj) * T_ + t];
#pragma unroll
        for (int jj = 0; jj < 4; ++jj) {
            wx0[jj] = W_hx[(size_t)xv[jj] * H_ + c0];
            wx1[jj] = W_hx[(size_t)xv[jj] * H_ + c0 + 16];
        }

        const _Float16* ap = hc + (size_t)arow * H_ + kl;
        floatx4 acc0 = {0.f, 0.f, 0.f, 0.f}, acc1 = {0.f, 0.f, 0.f, 0.f};

        // K-loop: 8 blocks x 8 frags, register ping-pong; next block's 16 IF$ loads
        // issue ahead of current block's MFMAs -> latency hidden.
        half8 aA[8], aB[8];
        LOAD_BLK(aA, 0);
#pragma unroll
        for (int sb = 0; sb < 4; ++sb) {
            LOAD_BLK(aB, 2 * sb + 1);
            COMP_BLK(aA, 2 * sb);
            if (sb < 3) { LOAD_BLK(aA, 2 * sb + 2); }
            COMP_BLK(aB, 2 * sb + 1);
        }

        // publish h: packed (col j | col j+16) u32 atomic swap -> executes AT the IF$
#pragma unroll
        for (int jj = 0; jj < 4; ++jj) {
            float z0 = acc0[jj] + wx0[jj] + bh0;
            float z1 = acc1[jj] + wx1[jj] + bh1;
            _Float16 p0 = (_Float16)tanhf(z0), p1 = (_Float16)tanhf(z1);
            unsigned pv = ((unsigned)__builtin_bit_cast(unsigned short, p1) << 16)
                        |  (unsigned)__builtin_bit_cast(unsigned short, p0);
            unsigned* dst = (unsigned*)(hn + (size_t)(r0 + jj) * H_ + nb + 2 * l15);
            unsigned old = __hip_atomic_exchange(dst, pv, __ATOMIC_RELAXED,
                                                 __HIP_MEMORY_SCOPE_AGENT);
            asm volatile("" :: "v"(old));   // keep the returning (executed-at-IF$) form
        }

        // ---- barrier: zero cache maintenance; visibility came from the atomics ----
        __syncthreads();                     // vmcnt drain: all swaps executed at IF$
        if (tid == 0) {
            __builtin_amdgcn_fence(__ATOMIC_RELEASE, "workgroup");   // ordering only
            __hip_atomic_fetch_add(mycnt, 1u, __ATOMIC_RELAXED, __HIP_MEMORY_SCOPE_AGENT);
            while (__hip_atomic_load(mycnt, __ATOMIC_RELAXED, __HIP_MEMORY_SCOPE_AGENT)
                   < (unsigned)(64 * t))
                __builtin_amdgcn_s_sleep(2);
            __builtin_amdgcn_fence(__ATOMIC_ACQUIRE, "workgroup");   // ordering only
        }
        __syncthreads();
    }
}

// ---- out[b,c] = h[b,:] @ W_ph + b_p (fp32); h is in permuted storage order ----
__global__ void final_proj(const _Float16* __restrict__ h, const float* __restrict__ W_ph,
                           const float* __restrict__ b_p, float* __restrict__ out) {
    __shared__ float part[C_];
    const int b  = blockIdx.x;
    const int c  = threadIdx.x & (C_ - 1);
    const int hh = threadIdx.x >> 7;
    const int j0 = hh * (H_ / 2);
    float acc = 0.f;
#pragma unroll 4
    for (int s = j0; s < j0 + H_ / 2; ++s) {
        int k = (s & ~31) + ((s & 31) >> 1) + ((s & 1) << 4);   // sigma(s)
        acc = fmaf((float)h[(size_t)b * H_ + s], W_ph[k * C_ + c], acc);
    }
    if (hh) part[c] = acc;
    __syncthreads();
    if (!hh) out[b * C_ + c] = acc + part[c] + b_p[c];
}

extern "C" void kernel_launch(void* const* d_in, const int* in_sizes, int n_in,
                              void* d_out, int out_size, void* d_ws, size_t ws_size,
                              hipStream_t stream) {
    const int*   x    = (const int*)d_in[0];
    const float* W_hx = (const float*)d_in[1];
    const float* W_hh = (const float*)d_in[2];
    const float* W_ph = (const float*)d_in[3];
    const float* b_h  = (const float*)d_in[4];
    const float* b_p  = (const float*)d_in[5];
    float* out = (float*)d_out;

    char* ws = (char*)d_ws;
    _Float16* h0  = (_Float16*)ws;                                   // 1 MB
    _Float16* h1  = (_Float16*)(ws + (size_t)B_ * H_ * 2);           // 1 MB
    unsigned* cnt = (unsigned*)(ws + (size_t)2 * B_ * H_ * 2);       // 2 KB (512 u32)

    init_h<<<(B_ * H_) / 256, 256, 0, stream>>>(x, W_hx, b_h, h0, cnt);

    const int smem = 32 * BSTRIDE * 2;   // 131328 B
    hipFuncSetAttribute((const void*)rnn_steps,
                        hipFuncAttributeMaxDynamicSharedMemorySize, smem);

    const float* whh = W_hh; _Float16* ph0 = h0; _Float16* ph1 = h1;
    const int* px = x; const float* pwhx = W_hx; const float* pbh = b_h;
    unsigned* pcnt = cnt;
    void* args[] = {(void*)&whh, (void*)&ph0, (void*)&ph1,
                    (void*)&px, (void*)&pwhx, (void*)&pbh, (void*)&pcnt};
    hipError_t e = hipLaunchCooperativeKernel((void*)rnn_steps, dim3(256), dim3(256),
                                              args, smem, stream);
    if (e != hipSuccess) {
        // fallback: plain launch — 1 WG/CU x 256 WGs co-schedules on 256 CUs
        rnn_steps<<<dim3(256), dim3(256), smem, stream>>>(whh, ph0, ph1, px, pwhx, pbh, pcnt);
    }

    // h after t=511 lives in h1
    final_proj<<<B_, 256, 0, stream>>>(h1, W_ph, b_p, out);
}